// Round 9
// baseline (31.629 us; speedup 1.0000x reference)
//
#include <hip/hip_runtime.h>
#include <hip/hip_bf16.h>

#define NCELL 32
#define KTAB  2048

// ---------- proven round-2 closed form (unchanged numerics) ----------

__device__ __forceinline__ float cross_tau(float a, float b, float xs, float xb,
                                           bool need_right, bool open_b)
{
    const float eps    = 1e-10f;
    const float CLIPLO = -1.0f + 1e-6f;
    float v = a * xs + b;
    bool right = v > 0.0f;
    if (right != need_right) return 2.0f;
    bool small_a = fabsf(a) < eps;
    bool small_v = fabsf(v) < eps;
    float v_safe = small_v ? eps : v;
    float a_safe = small_a ? eps : a;
    float dxb = xb - xs;
    float arg_raw = a * dxb / v_safe;
    bool unreach = arg_raw <= CLIPLO;
    float tau = small_a ? (dxb / v_safe)
                        : (log1pf(fmaxf(arg_raw, CLIPLO)) / a_safe);
    if (open_b || small_v || unreach || (tau < 0.0f)) return 2.0f;
    return fminf(tau, 2.0f);
}

__device__ __forceinline__ void solve_point(float xs,
        const float* __restrict__ ta, const float* __restrict__ tb,
        const float* __restrict__ T0, const float* __restrict__ T1,
        const float* __restrict__ G0, const float* __restrict__ G1,
        float& z, float& lg)
{
    const float eps    = 1e-10f;
    const float CLIPLO = -1.0f + 1e-6f;
    const float invN   = 1.0f / (float)NCELL;

    int c = (int)floorf(xs * (float)NCELL);
    c = min(max(c, 0), NCELL - 1);
    float a = ta[c], b = tb[c];
    float v = a * xs + b;
    bool right = v > 0.0f;
    float xb = (right ? (float)(c + 1) : (float)c) * invN;
    bool open_b  = right ? (c == NCELL - 1) : (c == 0);
    bool small_a = fabsf(a) < eps;
    bool small_v = fabsf(v) < eps;
    float v_safe = small_v ? eps : v;
    float a_safe = small_a ? eps : a;
    float dxb = xb - xs;
    float arg_raw = a * dxb / v_safe;
    bool unreach = arg_raw <= CLIPLO;
    float tau0 = small_a ? (dxb / v_safe)
                         : (log1pf(fmaxf(arg_raw, CLIPLO)) / a_safe);
    bool blocked0 = open_b || small_v || unreach || (tau0 < 0.0f);
    bool hit0 = (!blocked0) && (tau0 <= 1.0f);

    float Xf, Df, lg_pre;
    int   Cf;
    if (hit0) {
        int k1   = right ? c + 1 : c;
        int idx0 = right ? k1 : NCELL - k1;
        const float* Tt = right ? T0 : T1;
        const float* Gg = right ? G0 : G1;
        float r    = 1.0f - tau0;
        float base = Tt[idx0];
        int m = idx0;
        #pragma unroll
        for (int bit = 16; bit; bit >>= 1) {
            int cand = m + bit;
            bool ok = (cand <= NCELL) && ((Tt[cand] - base) <= r);
            m = ok ? cand : m;
        }
        float r2 = r - (Tt[m] - base);
        lg_pre = a * tau0 + (Gg[m] - Gg[idx0]);
        int knot = right ? m : NCELL - m;
        Cf = right ? knot : knot - 1;
        Xf = (float)knot * invN;
        Df = r2;
    } else {
        lg_pre = 0.0f; Cf = c; Xf = xs; Df = 1.0f;
    }

    float A  = ta[Cf], Bc = tb[Cf];
    float V  = A * Xf + Bc;
    bool  sA = fabsf(A) < eps;
    float A_safe = sA ? eps : A;
    float f  = sA ? Df : (expm1f(A * Df) / A_safe);
    z  = Xf + V * f;
    lg = lg_pre + A * Df;
}

// Per-block table setup (A = B@theta, per-cell crossing times, prefix sums).
__device__ __forceinline__ void block_setup(
        const float* __restrict__ theta, const float* __restrict__ B,
        float* ta, float* tb, float* taur_s, float* taul_s,
        float* T0, float* T1, float* G0, float* G1)
{
    const int tid = threadIdx.x;
    const float invN = 1.0f / (float)NCELL;

    if (tid < 2 * NCELL) {
        float acc = 0.f;
        #pragma unroll
        for (int j = 0; j < NCELL + 1; ++j)
            acc += B[tid * (NCELL + 1) + j] * theta[j];
        if (tid & 1) tb[tid >> 1] = acc;
        else         ta[tid >> 1] = acc;
    }
    __syncthreads();

    if (tid < NCELL) {
        int cc = tid;
        float a = ta[cc], b = tb[cc];
        float xl = (float)cc * invN, xr = (float)(cc + 1) * invN;
        taur_s[cc] = cross_tau(a, b, xl, xr, true,  cc == NCELL - 1);
        taul_s[cc] = cross_tau(a, b, xr, xl, false, cc == 0);
    }
    __syncthreads();

    if (tid < NCELL) {
        int lane = tid;
        float v0 = taur_s[lane];
        float v1 = taul_s[NCELL - 1 - lane];
        float g0 = ta[lane] * v0;
        float g1 = ta[NCELL - 1 - lane] * v1;
        #pragma unroll
        for (int off = 1; off < NCELL; off <<= 1) {
            float o0 = __shfl_up(v0, off, 64);
            float o1 = __shfl_up(v1, off, 64);
            float o2 = __shfl_up(g0, off, 64);
            float o3 = __shfl_up(g1, off, 64);
            if (lane >= off) { v0 += o0; v1 += o1; g0 += o2; g1 += o3; }
        }
        T0[lane + 1] = v0; T1[lane + 1] = v1;
        G0[lane + 1] = g0; G1[lane + 1] = g1;
        if (lane == 0) { T0[0] = 0.f; T1[0] = 0.f; G0[0] = 0.f; G1[0] = 0.f; }
    }
    __syncthreads();
}

// ---------- fused kernel: every block builds its table, then lerps ----------
// Changes vs round 8:
//  (a) split z/lg tables (float, stride 4B) -> gathers use all 32 banks
//      (float2 stride-8B restricted to 16 even banks; round-7 counter showed
//      2.16M conflict cycles on that layout); zt[j]/zt[j+1] -> ds_read2_b32.
//  (b) x-loads hoisted above the table build: register-destined global loads
//      stay in flight across the build's VALU work (no vmcnt drain needed).

__global__ __launch_bounds__(512) void cpab_kernel(
    const float* __restrict__ x,
    const float* __restrict__ theta,
    const float* __restrict__ B,
    float* __restrict__ z_out,
    float* __restrict__ lg_out,
    int n)
{
    __shared__ float zt[KTAB + 1];
    __shared__ float lt[KTAB + 1];
    __shared__ float ta[NCELL], tb[NCELL];
    __shared__ float taur_s[NCELL], taul_s[NCELL];
    __shared__ float T0[NCELL + 1], T1[NCELL + 1];
    __shared__ float G0[NCELL + 1], G1[NCELL + 1];

    const int tid    = threadIdx.x;
    const int gid    = blockIdx.x * blockDim.x + tid;
    const int stride = gridDim.x * blockDim.x;
    const int n4     = n >> 2;

    const float4* __restrict__ x4 = (const float4*)x;
    float4* __restrict__ z4 = (float4*)z_out;
    float4* __restrict__ l4 = (float4*)lg_out;

    // ---- prefetch (up to 4 float4 = 16 points/thread) ----
    const int i0 = gid;
    const int i1 = gid + stride;
    const int i2 = gid + 2 * stride;
    const int i3 = gid + 3 * stride;
    float4 xv0, xv1, xv2, xv3;
    const bool v0 = i0 < n4, v1 = i1 < n4, v2 = i2 < n4, v3 = i3 < n4;
    if (v0) xv0 = x4[i0];
    if (v1) xv1 = x4[i1];
    if (v2) xv2 = x4[i2];
    if (v3) xv3 = x4[i3];

    // ---- per-block table build ----
    block_setup(theta, B, ta, tb, taur_s, taul_s, T0, T1, G0, G1);

    const float invK = 1.0f / (float)KTAB;
    for (int j = tid; j <= KTAB; j += 512) {
        float z, lg;
        solve_point((float)j * invK, ta, tb, T0, T1, G0, G1, z, lg);
        zt[j] = z;
        lt[j] = lg;
    }
    __syncthreads();

    // ---- lerp + store ----
    const float Kf = (float)KTAB;

    #define LERP4(xv, zv, lv)                                   \
        {                                                       \
            _Pragma("unroll")                                   \
            for (int q = 0; q < 4; ++q) {                       \
                float t  = (&(xv).x)[q] * Kf;                   \
                float jf = floorf(t);                           \
                int   j  = min(max((int)jf, 0), KTAB - 1);      \
                float f  = t - (float)j;                        \
                float z0 = zt[j], z1 = zt[j + 1];               \
                float l0 = lt[j], l1 = lt[j + 1];               \
                (&(zv).x)[q] = fmaf(f, z1 - z0, z0);            \
                (&(lv).x)[q] = fmaf(f, l1 - l0, l0);            \
            }                                                   \
        }

    if (v0) { float4 zv, lv; LERP4(xv0, zv, lv); z4[i0] = zv; l4[i0] = lv; }
    if (v1) { float4 zv, lv; LERP4(xv1, zv, lv); z4[i1] = zv; l4[i1] = lv; }
    if (v2) { float4 zv, lv; LERP4(xv2, zv, lv); z4[i2] = zv; l4[i2] = lv; }
    if (v3) { float4 zv, lv; LERP4(xv3, zv, lv); z4[i3] = zv; l4[i3] = lv; }

    // tail (n not divisible by 4) + any residual beyond 4 iters
    for (int i = gid + 4 * stride; i < n4; i += stride) {
        float4 xv = x4[i], zv, lv;
        LERP4(xv, zv, lv);
        z4[i] = zv;
        l4[i] = lv;
    }
    for (int i = (n4 << 2) + gid; i < n; i += stride) {
        float t  = x[i] * Kf;
        float jf = floorf(t);
        int   j  = min(max((int)jf, 0), KTAB - 1);
        float f  = t - (float)j;
        float z0 = zt[j], z1 = zt[j + 1];
        float l0 = lt[j], l1 = lt[j + 1];
        z_out[i]  = fmaf(f, z1 - z0, z0);
        lg_out[i] = fmaf(f, l1 - l0, l0);
    }
    #undef LERP4
}

extern "C" void kernel_launch(void* const* d_in, const int* in_sizes, int n_in,
                              void* d_out, int out_size, void* d_ws, size_t ws_size,
                              hipStream_t stream)
{
    const float* x     = (const float*)d_in[0];
    const float* theta = (const float*)d_in[1];
    const float* B     = (const float*)d_in[2];
    float* out = (float*)d_out;

    const int n = in_sizes[0];
    float* z_out  = out;
    float* lg_out = out + n;

    // 1024 blocks x 512 threads: 4 blocks/CU x 8 waves = 32 waves/CU,
    // LDS ~17.4 KB/block -> 70 KB/CU. n4 = 2.1M float4 -> exactly 4/thread.
    cpab_kernel<<<1024, 512, 0, stream>>>(x, theta, B, z_out, lg_out, n);
}

// Round 10
// 27.373 us; speedup vs baseline: 1.1555x; 1.1555x over previous
//
#include <hip/hip_runtime.h>
#include <hip/hip_bf16.h>
#include <hip/hip_fp16.h>

#define NCELL 32
#define KTAB  2048

// ---------- proven round-2 closed form (unchanged numerics) ----------

__device__ __forceinline__ float cross_tau(float a, float b, float xs, float xb,
                                           bool need_right, bool open_b)
{
    const float eps    = 1e-10f;
    const float CLIPLO = -1.0f + 1e-6f;
    float v = a * xs + b;
    bool right = v > 0.0f;
    if (right != need_right) return 2.0f;
    bool small_a = fabsf(a) < eps;
    bool small_v = fabsf(v) < eps;
    float v_safe = small_v ? eps : v;
    float a_safe = small_a ? eps : a;
    float dxb = xb - xs;
    float arg_raw = a * dxb / v_safe;
    bool unreach = arg_raw <= CLIPLO;
    float tau = small_a ? (dxb / v_safe)
                        : (log1pf(fmaxf(arg_raw, CLIPLO)) / a_safe);
    if (open_b || small_v || unreach || (tau < 0.0f)) return 2.0f;
    return fminf(tau, 2.0f);
}

__device__ __forceinline__ void solve_point(float xs,
        const float* __restrict__ ta, const float* __restrict__ tb,
        const float* __restrict__ T0, const float* __restrict__ T1,
        const float* __restrict__ G0, const float* __restrict__ G1,
        float& z, float& lg)
{
    const float eps    = 1e-10f;
    const float CLIPLO = -1.0f + 1e-6f;
    const float invN   = 1.0f / (float)NCELL;

    int c = (int)floorf(xs * (float)NCELL);
    c = min(max(c, 0), NCELL - 1);
    float a = ta[c], b = tb[c];
    float v = a * xs + b;
    bool right = v > 0.0f;
    float xb = (right ? (float)(c + 1) : (float)c) * invN;
    bool open_b  = right ? (c == NCELL - 1) : (c == 0);
    bool small_a = fabsf(a) < eps;
    bool small_v = fabsf(v) < eps;
    float v_safe = small_v ? eps : v;
    float a_safe = small_a ? eps : a;
    float dxb = xb - xs;
    float arg_raw = a * dxb / v_safe;
    bool unreach = arg_raw <= CLIPLO;
    float tau0 = small_a ? (dxb / v_safe)
                         : (log1pf(fmaxf(arg_raw, CLIPLO)) / a_safe);
    bool blocked0 = open_b || small_v || unreach || (tau0 < 0.0f);
    bool hit0 = (!blocked0) && (tau0 <= 1.0f);

    float Xf, Df, lg_pre;
    int   Cf;
    if (hit0) {
        int k1   = right ? c + 1 : c;
        int idx0 = right ? k1 : NCELL - k1;
        const float* Tt = right ? T0 : T1;
        const float* Gg = right ? G0 : G1;
        float r    = 1.0f - tau0;
        float base = Tt[idx0];
        int m = idx0;
        #pragma unroll
        for (int bit = 16; bit; bit >>= 1) {
            int cand = m + bit;
            bool ok = (cand <= NCELL) && ((Tt[cand] - base) <= r);
            m = ok ? cand : m;
        }
        float r2 = r - (Tt[m] - base);
        lg_pre = a * tau0 + (Gg[m] - Gg[idx0]);
        int knot = right ? m : NCELL - m;
        Cf = right ? knot : knot - 1;
        Xf = (float)knot * invN;
        Df = r2;
    } else {
        lg_pre = 0.0f; Cf = c; Xf = xs; Df = 1.0f;
    }

    float A  = ta[Cf], Bc = tb[Cf];
    float V  = A * Xf + Bc;
    bool  sA = fabsf(A) < eps;
    float A_safe = sA ? eps : A;
    float f  = sA ? Df : (expm1f(A * Df) / A_safe);
    z  = Xf + V * f;
    lg = lg_pre + A * Df;
}

// Per-block table setup (A = B@theta, per-cell crossing times, prefix sums).
__device__ __forceinline__ void block_setup(
        const float* __restrict__ theta, const float* __restrict__ B,
        float* ta, float* tb, float* taur_s, float* taul_s,
        float* T0, float* T1, float* G0, float* G1)
{
    const int tid = threadIdx.x;
    const float invN = 1.0f / (float)NCELL;

    if (tid < 2 * NCELL) {
        float acc = 0.f;
        #pragma unroll
        for (int j = 0; j < NCELL + 1; ++j)
            acc += B[tid * (NCELL + 1) + j] * theta[j];
        if (tid & 1) tb[tid >> 1] = acc;
        else         ta[tid >> 1] = acc;
    }
    __syncthreads();

    if (tid < NCELL) {
        int cc = tid;
        float a = ta[cc], b = tb[cc];
        float xl = (float)cc * invN, xr = (float)(cc + 1) * invN;
        taur_s[cc] = cross_tau(a, b, xl, xr, true,  cc == NCELL - 1);
        taul_s[cc] = cross_tau(a, b, xr, xl, false, cc == 0);
    }
    __syncthreads();

    if (tid < NCELL) {
        int lane = tid;
        float v0 = taur_s[lane];
        float v1 = taul_s[NCELL - 1 - lane];
        float g0 = ta[lane] * v0;
        float g1 = ta[NCELL - 1 - lane] * v1;
        #pragma unroll
        for (int off = 1; off < NCELL; off <<= 1) {
            float o0 = __shfl_up(v0, off, 64);
            float o1 = __shfl_up(v1, off, 64);
            float o2 = __shfl_up(g0, off, 64);
            float o3 = __shfl_up(g1, off, 64);
            if (lane >= off) { v0 += o0; v1 += o1; g0 += o2; g1 += o3; }
        }
        T0[lane + 1] = v0; T1[lane + 1] = v1;
        G0[lane + 1] = g0; G1[lane + 1] = g1;
        if (lane == 0) { T0[0] = 0.f; T1[0] = 0.f; G0[0] = 0.f; G1[0] = 0.f; }
    }
    __syncthreads();
}

// ---------- fused kernel: every block builds its table, then lerps ----------
// Round-8 structure (27.4 us), ONE change: table packed as __half2 (z,lg),
// 4 B/entry. Per point: ht[j], ht[j+1] are adjacent dwords -> one
// ds_read2_b32 (was two ds_read_b64); stride 4 B -> gathers hit all 32 banks
// (float2 stride-8 only used the 16 even banks; round-7 counter: 2.16M
// conflict cycles on that layout). f16 adds <=~7e-4 abs error (threshold 1.5e-2).

__global__ __launch_bounds__(512) void cpab_kernel(
    const float* __restrict__ x,
    const float* __restrict__ theta,
    const float* __restrict__ B,
    float* __restrict__ z_out,
    float* __restrict__ lg_out,
    int n)
{
    __shared__ __half2 htab[KTAB + 1];
    __shared__ float ta[NCELL], tb[NCELL];
    __shared__ float taur_s[NCELL], taul_s[NCELL];
    __shared__ float T0[NCELL + 1], T1[NCELL + 1];
    __shared__ float G0[NCELL + 1], G1[NCELL + 1];

    const int tid = threadIdx.x;

    block_setup(theta, B, ta, tb, taur_s, taul_s, T0, T1, G0, G1);

    const float invK = 1.0f / (float)KTAB;
    for (int j = tid; j <= KTAB; j += 512) {
        float z, lg;
        solve_point((float)j * invK, ta, tb, T0, T1, G0, G1, z, lg);
        htab[j] = __floats2half2_rn(z, lg);
    }
    __syncthreads();

    const float Kf = (float)KTAB;
    const int gid    = blockIdx.x * blockDim.x + tid;
    const int stride = gridDim.x * blockDim.x;
    const int n4     = n >> 2;

    const float4* __restrict__ x4 = (const float4*)x;
    float4* __restrict__ z4 = (float4*)z_out;
    float4* __restrict__ l4 = (float4*)lg_out;

    for (int i = gid; i < n4; i += stride) {
        float4 xv = x4[i];
        float4 zv, lv;
        #pragma unroll
        for (int q = 0; q < 4; ++q) {
            float xs = (&xv.x)[q];
            float t  = xs * Kf;
            float jf = floorf(t);
            int   j  = min(max((int)jf, 0), KTAB - 1);
            float f  = t - (float)j;
            float2 p0 = __half22float2(htab[j]);
            float2 p1 = __half22float2(htab[j + 1]);
            (&zv.x)[q] = fmaf(f, p1.x - p0.x, p0.x);
            (&lv.x)[q] = fmaf(f, p1.y - p0.y, p0.y);
        }
        z4[i] = zv;
        l4[i] = lv;
    }
    for (int i = (n4 << 2) + gid; i < n; i += stride) {
        float xs = x[i];
        float t  = xs * Kf;
        float jf = floorf(t);
        int   j  = min(max((int)jf, 0), KTAB - 1);
        float f  = t - (float)j;
        float2 p0 = __half22float2(htab[j]);
        float2 p1 = __half22float2(htab[j + 1]);
        z_out[i]  = fmaf(f, p1.x - p0.x, p0.x);
        lg_out[i] = fmaf(f, p1.y - p0.y, p0.y);
    }
}

extern "C" void kernel_launch(void* const* d_in, const int* in_sizes, int n_in,
                              void* d_out, int out_size, void* d_ws, size_t ws_size,
                              hipStream_t stream)
{
    const float* x     = (const float*)d_in[0];
    const float* theta = (const float*)d_in[1];
    const float* B     = (const float*)d_in[2];
    float* out = (float*)d_out;

    const int n = in_sizes[0];
    float* z_out  = out;
    float* lg_out = out + n;

    // 1024 blocks x 512 threads: 4 blocks/CU x 8 waves = 32 waves/CU,
    // LDS ~9.2 KB/block. n4 = 2.1M float4 -> exactly 4 iters/thread.
    cpab_kernel<<<1024, 512, 0, stream>>>(x, theta, B, z_out, lg_out, n);
}

// Round 11
// 27.276 us; speedup vs baseline: 1.1596x; 1.0036x over previous
//
#include <hip/hip_runtime.h>
#include <hip/hip_bf16.h>
#include <hip/hip_fp16.h>

#define NCELL 32
#define KTAB  2048

// ---------- proven round-2 closed form (unchanged numerics) ----------

__device__ __forceinline__ float cross_tau(float a, float b, float xs, float xb,
                                           bool need_right, bool open_b)
{
    const float eps    = 1e-10f;
    const float CLIPLO = -1.0f + 1e-6f;
    float v = a * xs + b;
    bool right = v > 0.0f;
    if (right != need_right) return 2.0f;
    bool small_a = fabsf(a) < eps;
    bool small_v = fabsf(v) < eps;
    float v_safe = small_v ? eps : v;
    float a_safe = small_a ? eps : a;
    float dxb = xb - xs;
    float arg_raw = a * dxb / v_safe;
    bool unreach = arg_raw <= CLIPLO;
    float tau = small_a ? (dxb / v_safe)
                        : (log1pf(fmaxf(arg_raw, CLIPLO)) / a_safe);
    if (open_b || small_v || unreach || (tau < 0.0f)) return 2.0f;
    return fminf(tau, 2.0f);
}

__device__ __forceinline__ void solve_point(float xs,
        const float* __restrict__ ta, const float* __restrict__ tb,
        const float* __restrict__ T0, const float* __restrict__ T1,
        const float* __restrict__ G0, const float* __restrict__ G1,
        float& z, float& lg)
{
    const float eps    = 1e-10f;
    const float CLIPLO = -1.0f + 1e-6f;
    const float invN   = 1.0f / (float)NCELL;

    int c = (int)floorf(xs * (float)NCELL);
    c = min(max(c, 0), NCELL - 1);
    float a = ta[c], b = tb[c];
    float v = a * xs + b;
    bool right = v > 0.0f;
    float xb = (right ? (float)(c + 1) : (float)c) * invN;
    bool open_b  = right ? (c == NCELL - 1) : (c == 0);
    bool small_a = fabsf(a) < eps;
    bool small_v = fabsf(v) < eps;
    float v_safe = small_v ? eps : v;
    float a_safe = small_a ? eps : a;
    float dxb = xb - xs;
    float arg_raw = a * dxb / v_safe;
    bool unreach = arg_raw <= CLIPLO;
    float tau0 = small_a ? (dxb / v_safe)
                         : (log1pf(fmaxf(arg_raw, CLIPLO)) / a_safe);
    bool blocked0 = open_b || small_v || unreach || (tau0 < 0.0f);
    bool hit0 = (!blocked0) && (tau0 <= 1.0f);

    float Xf, Df, lg_pre;
    int   Cf;
    if (hit0) {
        int k1   = right ? c + 1 : c;
        int idx0 = right ? k1 : NCELL - k1;
        const float* Tt = right ? T0 : T1;
        const float* Gg = right ? G0 : G1;
        float r    = 1.0f - tau0;
        float base = Tt[idx0];
        int m = idx0;
        #pragma unroll
        for (int bit = 16; bit; bit >>= 1) {
            int cand = m + bit;
            bool ok = (cand <= NCELL) && ((Tt[cand] - base) <= r);
            m = ok ? cand : m;
        }
        float r2 = r - (Tt[m] - base);
        lg_pre = a * tau0 + (Gg[m] - Gg[idx0]);
        int knot = right ? m : NCELL - m;
        Cf = right ? knot : knot - 1;
        Xf = (float)knot * invN;
        Df = r2;
    } else {
        lg_pre = 0.0f; Cf = c; Xf = xs; Df = 1.0f;
    }

    float A  = ta[Cf], Bc = tb[Cf];
    float V  = A * Xf + Bc;
    bool  sA = fabsf(A) < eps;
    float A_safe = sA ? eps : A;
    float f  = sA ? Df : (expm1f(A * Df) / A_safe);
    z  = Xf + V * f;
    lg = lg_pre + A * Df;
}

// Per-block table setup (A = B@theta, per-cell crossing times, prefix sums).
__device__ __forceinline__ void block_setup(
        const float* __restrict__ theta, const float* __restrict__ B,
        float* ta, float* tb, float* taur_s, float* taul_s,
        float* T0, float* T1, float* G0, float* G1)
{
    const int tid = threadIdx.x;
    const float invN = 1.0f / (float)NCELL;

    if (tid < 2 * NCELL) {
        float acc = 0.f;
        #pragma unroll
        for (int j = 0; j < NCELL + 1; ++j)
            acc += B[tid * (NCELL + 1) + j] * theta[j];
        if (tid & 1) tb[tid >> 1] = acc;
        else         ta[tid >> 1] = acc;
    }
    __syncthreads();

    if (tid < NCELL) {
        int cc = tid;
        float a = ta[cc], b = tb[cc];
        float xl = (float)cc * invN, xr = (float)(cc + 1) * invN;
        taur_s[cc] = cross_tau(a, b, xl, xr, true,  cc == NCELL - 1);
        taul_s[cc] = cross_tau(a, b, xr, xl, false, cc == 0);
    }
    __syncthreads();

    if (tid < NCELL) {
        int lane = tid;
        float v0 = taur_s[lane];
        float v1 = taul_s[NCELL - 1 - lane];
        float g0 = ta[lane] * v0;
        float g1 = ta[NCELL - 1 - lane] * v1;
        #pragma unroll
        for (int off = 1; off < NCELL; off <<= 1) {
            float o0 = __shfl_up(v0, off, 64);
            float o1 = __shfl_up(v1, off, 64);
            float o2 = __shfl_up(g0, off, 64);
            float o3 = __shfl_up(g1, off, 64);
            if (lane >= off) { v0 += o0; v1 += o1; g0 += o2; g1 += o3; }
        }
        T0[lane + 1] = v0; T1[lane + 1] = v1;
        G0[lane + 1] = g0; G1[lane + 1] = g1;
        if (lane == 0) { T0[0] = 0.f; T1[0] = 0.f; G0[0] = 0.f; G1[0] = 0.f; }
    }
    __syncthreads();
}

// ---------- fused kernel: every block builds its table, then lerps ----------
// Round-10 structure (27.4 us), ONE change: streaming loop fully unrolled
// AFTER the table barrier -- all 4 independent global_load_dwordx4 issued
// back-to-back before any lerp (4x the in-flight loads per thread).
// (Round 9's version hoisted loads BEFORE block_setup's __syncthreads,
// whose vmcnt(0) drain serialized them; post-barrier placement avoids that.)

__global__ __launch_bounds__(512) void cpab_kernel(
    const float* __restrict__ x,
    const float* __restrict__ theta,
    const float* __restrict__ B,
    float* __restrict__ z_out,
    float* __restrict__ lg_out,
    int n)
{
    __shared__ __half2 htab[KTAB + 1];
    __shared__ float ta[NCELL], tb[NCELL];
    __shared__ float taur_s[NCELL], taul_s[NCELL];
    __shared__ float T0[NCELL + 1], T1[NCELL + 1];
    __shared__ float G0[NCELL + 1], G1[NCELL + 1];

    const int tid = threadIdx.x;

    block_setup(theta, B, ta, tb, taur_s, taul_s, T0, T1, G0, G1);

    const float invK = 1.0f / (float)KTAB;
    for (int j = tid; j <= KTAB; j += 512) {
        float z, lg;
        solve_point((float)j * invK, ta, tb, T0, T1, G0, G1, z, lg);
        htab[j] = __floats2half2_rn(z, lg);
    }
    __syncthreads();

    const float Kf = (float)KTAB;
    const int gid    = blockIdx.x * blockDim.x + tid;
    const int stride = gridDim.x * blockDim.x;
    const int n4     = n >> 2;

    const float4* __restrict__ x4 = (const float4*)x;
    float4* __restrict__ z4 = (float4*)z_out;
    float4* __restrict__ l4 = (float4*)lg_out;

    #define LERP4(xv, zv, lv)                                   \
        {                                                       \
            _Pragma("unroll")                                   \
            for (int q = 0; q < 4; ++q) {                       \
                float t  = (&(xv).x)[q] * Kf;                   \
                float jf = floorf(t);                           \
                int   j  = min(max((int)jf, 0), KTAB - 1);      \
                float f  = t - (float)j;                        \
                float2 p0 = __half22float2(htab[j]);            \
                float2 p1 = __half22float2(htab[j + 1]);        \
                (&(zv).x)[q] = fmaf(f, p1.x - p0.x, p0.x);      \
                (&(lv).x)[q] = fmaf(f, p1.y - p0.y, p0.y);      \
            }                                                   \
        }

    // main unrolled body: 4 loads in flight, then 4 lerp+store groups
    const int i0 = gid;
    const int i1 = gid + stride;
    const int i2 = gid + 2 * stride;
    const int i3 = gid + 3 * stride;
    const bool v0 = i0 < n4, v1 = i1 < n4, v2 = i2 < n4, v3 = i3 < n4;
    float4 xv0, xv1, xv2, xv3;
    if (v0) xv0 = x4[i0];
    if (v1) xv1 = x4[i1];
    if (v2) xv2 = x4[i2];
    if (v3) xv3 = x4[i3];

    if (v0) { float4 zv, lv; LERP4(xv0, zv, lv); z4[i0] = zv; l4[i0] = lv; }
    if (v1) { float4 zv, lv; LERP4(xv1, zv, lv); z4[i1] = zv; l4[i1] = lv; }
    if (v2) { float4 zv, lv; LERP4(xv2, zv, lv); z4[i2] = zv; l4[i2] = lv; }
    if (v3) { float4 zv, lv; LERP4(xv3, zv, lv); z4[i3] = zv; l4[i3] = lv; }

    // residual (grid smaller than n4/4) + scalar tail (n % 4)
    for (int i = gid + 4 * stride; i < n4; i += stride) {
        float4 xv = x4[i], zv, lv;
        LERP4(xv, zv, lv);
        z4[i] = zv;
        l4[i] = lv;
    }
    for (int i = (n4 << 2) + gid; i < n; i += stride) {
        float t  = x[i] * Kf;
        float jf = floorf(t);
        int   j  = min(max((int)jf, 0), KTAB - 1);
        float f  = t - (float)j;
        float2 p0 = __half22float2(htab[j]);
        float2 p1 = __half22float2(htab[j + 1]);
        z_out[i]  = fmaf(f, p1.x - p0.x, p0.x);
        lg_out[i] = fmaf(f, p1.y - p0.y, p0.y);
    }
    #undef LERP4
}

extern "C" void kernel_launch(void* const* d_in, const int* in_sizes, int n_in,
                              void* d_out, int out_size, void* d_ws, size_t ws_size,
                              hipStream_t stream)
{
    const float* x     = (const float*)d_in[0];
    const float* theta = (const float*)d_in[1];
    const float* B     = (const float*)d_in[2];
    float* out = (float*)d_out;

    const int n = in_sizes[0];
    float* z_out  = out;
    float* lg_out = out + n;

    // 1024 blocks x 512 threads: 4 blocks/CU x 8 waves = 32 waves/CU,
    // LDS ~9.2 KB/block. n4 = 2.1M float4 -> exactly 4 iters/thread.
    cpab_kernel<<<1024, 512, 0, stream>>>(x, theta, B, z_out, lg_out, n);
}

// Round 12
// 25.337 us; speedup vs baseline: 1.2483x; 1.0765x over previous
//
#include <hip/hip_runtime.h>
#include <hip/hip_bf16.h>
#include <hip/hip_fp16.h>

#define NCELL 32
#define KTAB  1024

// ---------- proven round-2 closed form (unchanged numerics) ----------

__device__ __forceinline__ float cross_tau(float a, float b, float xs, float xb,
                                           bool need_right, bool open_b)
{
    const float eps    = 1e-10f;
    const float CLIPLO = -1.0f + 1e-6f;
    float v = a * xs + b;
    bool right = v > 0.0f;
    if (right != need_right) return 2.0f;
    bool small_a = fabsf(a) < eps;
    bool small_v = fabsf(v) < eps;
    float v_safe = small_v ? eps : v;
    float a_safe = small_a ? eps : a;
    float dxb = xb - xs;
    float arg_raw = a * dxb / v_safe;
    bool unreach = arg_raw <= CLIPLO;
    float tau = small_a ? (dxb / v_safe)
                        : (log1pf(fmaxf(arg_raw, CLIPLO)) / a_safe);
    if (open_b || small_v || unreach || (tau < 0.0f)) return 2.0f;
    return fminf(tau, 2.0f);
}

__device__ __forceinline__ void solve_point(float xs,
        const float* __restrict__ ta, const float* __restrict__ tb,
        const float* __restrict__ T0, const float* __restrict__ T1,
        const float* __restrict__ G0, const float* __restrict__ G1,
        float& z, float& lg)
{
    const float eps    = 1e-10f;
    const float CLIPLO = -1.0f + 1e-6f;
    const float invN   = 1.0f / (float)NCELL;

    int c = (int)floorf(xs * (float)NCELL);
    c = min(max(c, 0), NCELL - 1);
    float a = ta[c], b = tb[c];
    float v = a * xs + b;
    bool right = v > 0.0f;
    float xb = (right ? (float)(c + 1) : (float)c) * invN;
    bool open_b  = right ? (c == NCELL - 1) : (c == 0);
    bool small_a = fabsf(a) < eps;
    bool small_v = fabsf(v) < eps;
    float v_safe = small_v ? eps : v;
    float a_safe = small_a ? eps : a;
    float dxb = xb - xs;
    float arg_raw = a * dxb / v_safe;
    bool unreach = arg_raw <= CLIPLO;
    float tau0 = small_a ? (dxb / v_safe)
                         : (log1pf(fmaxf(arg_raw, CLIPLO)) / a_safe);
    bool blocked0 = open_b || small_v || unreach || (tau0 < 0.0f);
    bool hit0 = (!blocked0) && (tau0 <= 1.0f);

    float Xf, Df, lg_pre;
    int   Cf;
    if (hit0) {
        int k1   = right ? c + 1 : c;
        int idx0 = right ? k1 : NCELL - k1;
        const float* Tt = right ? T0 : T1;
        const float* Gg = right ? G0 : G1;
        float r    = 1.0f - tau0;
        float base = Tt[idx0];
        int m = idx0;
        #pragma unroll
        for (int bit = 16; bit; bit >>= 1) {
            int cand = m + bit;
            bool ok = (cand <= NCELL) && ((Tt[cand] - base) <= r);
            m = ok ? cand : m;
        }
        float r2 = r - (Tt[m] - base);
        lg_pre = a * tau0 + (Gg[m] - Gg[idx0]);
        int knot = right ? m : NCELL - m;
        Cf = right ? knot : knot - 1;
        Xf = (float)knot * invN;
        Df = r2;
    } else {
        lg_pre = 0.0f; Cf = c; Xf = xs; Df = 1.0f;
    }

    float A  = ta[Cf], Bc = tb[Cf];
    float V  = A * Xf + Bc;
    bool  sA = fabsf(A) < eps;
    float A_safe = sA ? eps : A;
    float f  = sA ? Df : (expm1f(A * Df) / A_safe);
    z  = Xf + V * f;
    lg = lg_pre + A * Df;
}

// Per-block table setup (A = B@theta, per-cell crossing times, prefix sums).
__device__ __forceinline__ void block_setup(
        const float* __restrict__ theta, const float* __restrict__ B,
        float* ta, float* tb, float* taur_s, float* taul_s,
        float* T0, float* T1, float* G0, float* G1)
{
    const int tid = threadIdx.x;
    const float invN = 1.0f / (float)NCELL;

    if (tid < 2 * NCELL) {
        float acc = 0.f;
        #pragma unroll
        for (int j = 0; j < NCELL + 1; ++j)
            acc += B[tid * (NCELL + 1) + j] * theta[j];
        if (tid & 1) tb[tid >> 1] = acc;
        else         ta[tid >> 1] = acc;
    }
    __syncthreads();

    if (tid < NCELL) {
        int cc = tid;
        float a = ta[cc], b = tb[cc];
        float xl = (float)cc * invN, xr = (float)(cc + 1) * invN;
        taur_s[cc] = cross_tau(a, b, xl, xr, true,  cc == NCELL - 1);
        taul_s[cc] = cross_tau(a, b, xr, xl, false, cc == 0);
    }
    __syncthreads();

    if (tid < NCELL) {
        int lane = tid;
        float v0 = taur_s[lane];
        float v1 = taul_s[NCELL - 1 - lane];
        float g0 = ta[lane] * v0;
        float g1 = ta[NCELL - 1 - lane] * v1;
        #pragma unroll
        for (int off = 1; off < NCELL; off <<= 1) {
            float o0 = __shfl_up(v0, off, 64);
            float o1 = __shfl_up(v1, off, 64);
            float o2 = __shfl_up(g0, off, 64);
            float o3 = __shfl_up(g1, off, 64);
            if (lane >= off) { v0 += o0; v1 += o1; g0 += o2; g1 += o3; }
        }
        T0[lane + 1] = v0; T1[lane + 1] = v1;
        G0[lane + 1] = g0; G1[lane + 1] = g1;
        if (lane == 0) { T0[0] = 0.f; T1[0] = 0.f; G0[0] = 0.f; G1[0] = 0.f; }
    }
    __syncthreads();
}

// ---------- fused kernel: every block builds its table, then lerps ----------
// Round-11 structure, ONE change: KTAB 2048 -> 1024. Halves the redundant
// per-block build (per CU: 4 blocks x 1025 solves vs x 2049), the largest
// identified non-BW cost (~4-5 us of VALU-saturated prologue). Error math:
// phi is C1 -> z lerp error ~h^2|phi''|/8 ~ 1e-6; lg has slope kinks
// |da|<~3 -> err <= |da|h/4 ~ 7e-4 + f16 table ~5e-4, all << 1.54e-2.

__global__ __launch_bounds__(512) void cpab_kernel(
    const float* __restrict__ x,
    const float* __restrict__ theta,
    const float* __restrict__ B,
    float* __restrict__ z_out,
    float* __restrict__ lg_out,
    int n)
{
    __shared__ __half2 htab[KTAB + 1];
    __shared__ float ta[NCELL], tb[NCELL];
    __shared__ float taur_s[NCELL], taul_s[NCELL];
    __shared__ float T0[NCELL + 1], T1[NCELL + 1];
    __shared__ float G0[NCELL + 1], G1[NCELL + 1];

    const int tid = threadIdx.x;

    block_setup(theta, B, ta, tb, taur_s, taul_s, T0, T1, G0, G1);

    const float invK = 1.0f / (float)KTAB;
    for (int j = tid; j <= KTAB; j += 512) {
        float z, lg;
        solve_point((float)j * invK, ta, tb, T0, T1, G0, G1, z, lg);
        htab[j] = __floats2half2_rn(z, lg);
    }
    __syncthreads();

    const float Kf = (float)KTAB;
    const int gid    = blockIdx.x * blockDim.x + tid;
    const int stride = gridDim.x * blockDim.x;
    const int n4     = n >> 2;

    const float4* __restrict__ x4 = (const float4*)x;
    float4* __restrict__ z4 = (float4*)z_out;
    float4* __restrict__ l4 = (float4*)lg_out;

    #define LERP4(xv, zv, lv)                                   \
        {                                                       \
            _Pragma("unroll")                                   \
            for (int q = 0; q < 4; ++q) {                       \
                float t  = (&(xv).x)[q] * Kf;                   \
                float jf = floorf(t);                           \
                int   j  = min(max((int)jf, 0), KTAB - 1);      \
                float f  = t - (float)j;                        \
                float2 p0 = __half22float2(htab[j]);            \
                float2 p1 = __half22float2(htab[j + 1]);        \
                (&(zv).x)[q] = fmaf(f, p1.x - p0.x, p0.x);      \
                (&(lv).x)[q] = fmaf(f, p1.y - p0.y, p0.y);      \
            }                                                   \
        }

    // main unrolled body: 4 loads in flight, then 4 lerp+store groups
    const int i0 = gid;
    const int i1 = gid + stride;
    const int i2 = gid + 2 * stride;
    const int i3 = gid + 3 * stride;
    const bool v0 = i0 < n4, v1 = i1 < n4, v2 = i2 < n4, v3 = i3 < n4;
    float4 xv0, xv1, xv2, xv3;
    if (v0) xv0 = x4[i0];
    if (v1) xv1 = x4[i1];
    if (v2) xv2 = x4[i2];
    if (v3) xv3 = x4[i3];

    if (v0) { float4 zv, lv; LERP4(xv0, zv, lv); z4[i0] = zv; l4[i0] = lv; }
    if (v1) { float4 zv, lv; LERP4(xv1, zv, lv); z4[i1] = zv; l4[i1] = lv; }
    if (v2) { float4 zv, lv; LERP4(xv2, zv, lv); z4[i2] = zv; l4[i2] = lv; }
    if (v3) { float4 zv, lv; LERP4(xv3, zv, lv); z4[i3] = zv; l4[i3] = lv; }

    // residual (grid smaller than n4/4) + scalar tail (n % 4)
    for (int i = gid + 4 * stride; i < n4; i += stride) {
        float4 xv = x4[i], zv, lv;
        LERP4(xv, zv, lv);
        z4[i] = zv;
        l4[i] = lv;
    }
    for (int i = (n4 << 2) + gid; i < n; i += stride) {
        float t  = x[i] * Kf;
        float jf = floorf(t);
        int   j  = min(max((int)jf, 0), KTAB - 1);
        float f  = t - (float)j;
        float2 p0 = __half22float2(htab[j]);
        float2 p1 = __half22float2(htab[j + 1]);
        z_out[i]  = fmaf(f, p1.x - p0.x, p0.x);
        lg_out[i] = fmaf(f, p1.y - p0.y, p0.y);
    }
    #undef LERP4
}

extern "C" void kernel_launch(void* const* d_in, const int* in_sizes, int n_in,
                              void* d_out, int out_size, void* d_ws, size_t ws_size,
                              hipStream_t stream)
{
    const float* x     = (const float*)d_in[0];
    const float* theta = (const float*)d_in[1];
    const float* B     = (const float*)d_in[2];
    float* out = (float*)d_out;

    const int n = in_sizes[0];
    float* z_out  = out;
    float* lg_out = out + n;

    // 1024 blocks x 512 threads: 4 blocks/CU x 8 waves = 32 waves/CU,
    // LDS ~5.1 KB/block. n4 = 2.1M float4 -> exactly 4 iters/thread.
    cpab_kernel<<<1024, 512, 0, stream>>>(x, theta, B, z_out, lg_out, n);
}

// Round 13
// 24.308 us; speedup vs baseline: 1.3012x; 1.0423x over previous
//
#include <hip/hip_runtime.h>
#include <hip/hip_bf16.h>
#include <hip/hip_fp16.h>

#define NCELL 32
#define KTAB  256

// ---------- proven round-2 closed form (unchanged numerics) ----------

__device__ __forceinline__ float cross_tau(float a, float b, float xs, float xb,
                                           bool need_right, bool open_b)
{
    const float eps    = 1e-10f;
    const float CLIPLO = -1.0f + 1e-6f;
    float v = a * xs + b;
    bool right = v > 0.0f;
    if (right != need_right) return 2.0f;
    bool small_a = fabsf(a) < eps;
    bool small_v = fabsf(v) < eps;
    float v_safe = small_v ? eps : v;
    float a_safe = small_a ? eps : a;
    float dxb = xb - xs;
    float arg_raw = a * dxb / v_safe;
    bool unreach = arg_raw <= CLIPLO;
    float tau = small_a ? (dxb / v_safe)
                        : (log1pf(fmaxf(arg_raw, CLIPLO)) / a_safe);
    if (open_b || small_v || unreach || (tau < 0.0f)) return 2.0f;
    return fminf(tau, 2.0f);
}

__device__ __forceinline__ void solve_point(float xs,
        const float* __restrict__ ta, const float* __restrict__ tb,
        const float* __restrict__ T0, const float* __restrict__ T1,
        const float* __restrict__ G0, const float* __restrict__ G1,
        float& z, float& lg)
{
    const float eps    = 1e-10f;
    const float CLIPLO = -1.0f + 1e-6f;
    const float invN   = 1.0f / (float)NCELL;

    int c = (int)floorf(xs * (float)NCELL);
    c = min(max(c, 0), NCELL - 1);
    float a = ta[c], b = tb[c];
    float v = a * xs + b;
    bool right = v > 0.0f;
    float xb = (right ? (float)(c + 1) : (float)c) * invN;
    bool open_b  = right ? (c == NCELL - 1) : (c == 0);
    bool small_a = fabsf(a) < eps;
    bool small_v = fabsf(v) < eps;
    float v_safe = small_v ? eps : v;
    float a_safe = small_a ? eps : a;
    float dxb = xb - xs;
    float arg_raw = a * dxb / v_safe;
    bool unreach = arg_raw <= CLIPLO;
    float tau0 = small_a ? (dxb / v_safe)
                         : (log1pf(fmaxf(arg_raw, CLIPLO)) / a_safe);
    bool blocked0 = open_b || small_v || unreach || (tau0 < 0.0f);
    bool hit0 = (!blocked0) && (tau0 <= 1.0f);

    float Xf, Df, lg_pre;
    int   Cf;
    if (hit0) {
        int k1   = right ? c + 1 : c;
        int idx0 = right ? k1 : NCELL - k1;
        const float* Tt = right ? T0 : T1;
        const float* Gg = right ? G0 : G1;
        float r    = 1.0f - tau0;
        float base = Tt[idx0];
        int m = idx0;
        #pragma unroll
        for (int bit = 16; bit; bit >>= 1) {
            int cand = m + bit;
            bool ok = (cand <= NCELL) && ((Tt[cand] - base) <= r);
            m = ok ? cand : m;
        }
        float r2 = r - (Tt[m] - base);
        lg_pre = a * tau0 + (Gg[m] - Gg[idx0]);
        int knot = right ? m : NCELL - m;
        Cf = right ? knot : knot - 1;
        Xf = (float)knot * invN;
        Df = r2;
    } else {
        lg_pre = 0.0f; Cf = c; Xf = xs; Df = 1.0f;
    }

    float A  = ta[Cf], Bc = tb[Cf];
    float V  = A * Xf + Bc;
    bool  sA = fabsf(A) < eps;
    float A_safe = sA ? eps : A;
    float f  = sA ? Df : (expm1f(A * Df) / A_safe);
    z  = Xf + V * f;
    lg = lg_pre + A * Df;
}

// Per-block table setup (A = B@theta, per-cell crossing times, prefix sums).
__device__ __forceinline__ void block_setup(
        const float* __restrict__ theta, const float* __restrict__ B,
        float* ta, float* tb, float* taur_s, float* taul_s,
        float* T0, float* T1, float* G0, float* G1)
{
    const int tid = threadIdx.x;
    const float invN = 1.0f / (float)NCELL;

    if (tid < 2 * NCELL) {
        float acc = 0.f;
        #pragma unroll
        for (int j = 0; j < NCELL + 1; ++j)
            acc += B[tid * (NCELL + 1) + j] * theta[j];
        if (tid & 1) tb[tid >> 1] = acc;
        else         ta[tid >> 1] = acc;
    }
    __syncthreads();

    if (tid < NCELL) {
        int cc = tid;
        float a = ta[cc], b = tb[cc];
        float xl = (float)cc * invN, xr = (float)(cc + 1) * invN;
        taur_s[cc] = cross_tau(a, b, xl, xr, true,  cc == NCELL - 1);
        taul_s[cc] = cross_tau(a, b, xr, xl, false, cc == 0);
    }
    __syncthreads();

    if (tid < NCELL) {
        int lane = tid;
        float v0 = taur_s[lane];
        float v1 = taul_s[NCELL - 1 - lane];
        float g0 = ta[lane] * v0;
        float g1 = ta[NCELL - 1 - lane] * v1;
        #pragma unroll
        for (int off = 1; off < NCELL; off <<= 1) {
            float o0 = __shfl_up(v0, off, 64);
            float o1 = __shfl_up(v1, off, 64);
            float o2 = __shfl_up(g0, off, 64);
            float o3 = __shfl_up(g1, off, 64);
            if (lane >= off) { v0 += o0; v1 += o1; g0 += o2; g1 += o3; }
        }
        T0[lane + 1] = v0; T1[lane + 1] = v1;
        G0[lane + 1] = g0; G1[lane + 1] = g1;
        if (lane == 0) { T0[0] = 0.f; T1[0] = 0.f; G0[0] = 0.f; G1[0] = 0.f; }
    }
    __syncthreads();
}

// ---------- fused kernel: every block builds its table, then lerps ----------
// Round-12 structure, ONE change: KTAB 1024 -> 256. Build cost (the confirmed
// dominant non-BW cost; 2048->1024 gave -2 us exactly as build-halving
// predicts) drops to ~0.5 us. Error: z lerp ~h^2|phi''|/8 ~ 4e-6; lg kink
// error <= |da|h/4 ~ 1.5e-3 + f16 ~5e-4 -- all << 1.54e-2 threshold.

__global__ __launch_bounds__(512) void cpab_kernel(
    const float* __restrict__ x,
    const float* __restrict__ theta,
    const float* __restrict__ B,
    float* __restrict__ z_out,
    float* __restrict__ lg_out,
    int n)
{
    __shared__ __half2 htab[KTAB + 1];
    __shared__ float ta[NCELL], tb[NCELL];
    __shared__ float taur_s[NCELL], taul_s[NCELL];
    __shared__ float T0[NCELL + 1], T1[NCELL + 1];
    __shared__ float G0[NCELL + 1], G1[NCELL + 1];

    const int tid = threadIdx.x;

    block_setup(theta, B, ta, tb, taur_s, taul_s, T0, T1, G0, G1);

    const float invK = 1.0f / (float)KTAB;
    if (tid <= KTAB) {
        float z, lg;
        solve_point((float)tid * invK, ta, tb, T0, T1, G0, G1, z, lg);
        htab[tid] = __floats2half2_rn(z, lg);
    }
    __syncthreads();

    const float Kf = (float)KTAB;
    const int gid    = blockIdx.x * blockDim.x + tid;
    const int stride = gridDim.x * blockDim.x;
    const int n4     = n >> 2;

    const float4* __restrict__ x4 = (const float4*)x;
    float4* __restrict__ z4 = (float4*)z_out;
    float4* __restrict__ l4 = (float4*)lg_out;

    #define LERP4(xv, zv, lv)                                   \
        {                                                       \
            _Pragma("unroll")                                   \
            for (int q = 0; q < 4; ++q) {                       \
                float t  = (&(xv).x)[q] * Kf;                   \
                float jf = floorf(t);                           \
                int   j  = min(max((int)jf, 0), KTAB - 1);      \
                float f  = t - (float)j;                        \
                float2 p0 = __half22float2(htab[j]);            \
                float2 p1 = __half22float2(htab[j + 1]);        \
                (&(zv).x)[q] = fmaf(f, p1.x - p0.x, p0.x);      \
                (&(lv).x)[q] = fmaf(f, p1.y - p0.y, p0.y);      \
            }                                                   \
        }

    // main unrolled body: 4 loads in flight, then 4 lerp+store groups
    const int i0 = gid;
    const int i1 = gid + stride;
    const int i2 = gid + 2 * stride;
    const int i3 = gid + 3 * stride;
    const bool v0 = i0 < n4, v1 = i1 < n4, v2 = i2 < n4, v3 = i3 < n4;
    float4 xv0, xv1, xv2, xv3;
    if (v0) xv0 = x4[i0];
    if (v1) xv1 = x4[i1];
    if (v2) xv2 = x4[i2];
    if (v3) xv3 = x4[i3];

    if (v0) { float4 zv, lv; LERP4(xv0, zv, lv); z4[i0] = zv; l4[i0] = lv; }
    if (v1) { float4 zv, lv; LERP4(xv1, zv, lv); z4[i1] = zv; l4[i1] = lv; }
    if (v2) { float4 zv, lv; LERP4(xv2, zv, lv); z4[i2] = zv; l4[i2] = lv; }
    if (v3) { float4 zv, lv; LERP4(xv3, zv, lv); z4[i3] = zv; l4[i3] = lv; }

    // residual (grid smaller than n4/4) + scalar tail (n % 4)
    for (int i = gid + 4 * stride; i < n4; i += stride) {
        float4 xv = x4[i], zv, lv;
        LERP4(xv, zv, lv);
        z4[i] = zv;
        l4[i] = lv;
    }
    for (int i = (n4 << 2) + gid; i < n; i += stride) {
        float t  = x[i] * Kf;
        float jf = floorf(t);
        int   j  = min(max((int)jf, 0), KTAB - 1);
        float f  = t - (float)j;
        float2 p0 = __half22float2(htab[j]);
        float2 p1 = __half22float2(htab[j + 1]);
        z_out[i]  = fmaf(f, p1.x - p0.x, p0.x);
        lg_out[i] = fmaf(f, p1.y - p0.y, p0.y);
    }
    #undef LERP4
}

extern "C" void kernel_launch(void* const* d_in, const int* in_sizes, int n_in,
                              void* d_out, int out_size, void* d_ws, size_t ws_size,
                              hipStream_t stream)
{
    const float* x     = (const float*)d_in[0];
    const float* theta = (const float*)d_in[1];
    const float* B     = (const float*)d_in[2];
    float* out = (float*)d_out;

    const int n = in_sizes[0];
    float* z_out  = out;
    float* lg_out = out + n;

    // 1024 blocks x 512 threads: 4 blocks/CU x 8 waves = 32 waves/CU,
    // LDS ~2 KB/block. n4 = 2.1M float4 -> exactly 4 iters/thread.
    cpab_kernel<<<1024, 512, 0, stream>>>(x, theta, B, z_out, lg_out, n);
}

// Round 14
// 22.232 us; speedup vs baseline: 1.4227x; 1.0934x over previous
//
#include <hip/hip_runtime.h>
#include <hip/hip_bf16.h>
#include <hip/hip_fp16.h>

#define NCELL 32
#define KTAB  256

typedef float f32x4 __attribute__((ext_vector_type(4)));

// ---------- proven round-2 closed form (unchanged numerics) ----------

__device__ __forceinline__ float cross_tau(float a, float b, float xs, float xb,
                                           bool need_right, bool open_b)
{
    const float eps    = 1e-10f;
    const float CLIPLO = -1.0f + 1e-6f;
    float v = a * xs + b;
    bool right = v > 0.0f;
    if (right != need_right) return 2.0f;
    bool small_a = fabsf(a) < eps;
    bool small_v = fabsf(v) < eps;
    float v_safe = small_v ? eps : v;
    float a_safe = small_a ? eps : a;
    float dxb = xb - xs;
    float arg_raw = a * dxb / v_safe;
    bool unreach = arg_raw <= CLIPLO;
    float tau = small_a ? (dxb / v_safe)
                        : (log1pf(fmaxf(arg_raw, CLIPLO)) / a_safe);
    if (open_b || small_v || unreach || (tau < 0.0f)) return 2.0f;
    return fminf(tau, 2.0f);
}

__device__ __forceinline__ void solve_point(float xs,
        const float* __restrict__ ta, const float* __restrict__ tb,
        const float* __restrict__ T0, const float* __restrict__ T1,
        const float* __restrict__ G0, const float* __restrict__ G1,
        float& z, float& lg)
{
    const float eps    = 1e-10f;
    const float CLIPLO = -1.0f + 1e-6f;
    const float invN   = 1.0f / (float)NCELL;

    int c = (int)floorf(xs * (float)NCELL);
    c = min(max(c, 0), NCELL - 1);
    float a = ta[c], b = tb[c];
    float v = a * xs + b;
    bool right = v > 0.0f;
    float xb = (right ? (float)(c + 1) : (float)c) * invN;
    bool open_b  = right ? (c == NCELL - 1) : (c == 0);
    bool small_a = fabsf(a) < eps;
    bool small_v = fabsf(v) < eps;
    float v_safe = small_v ? eps : v;
    float a_safe = small_a ? eps : a;
    float dxb = xb - xs;
    float arg_raw = a * dxb / v_safe;
    bool unreach = arg_raw <= CLIPLO;
    float tau0 = small_a ? (dxb / v_safe)
                         : (log1pf(fmaxf(arg_raw, CLIPLO)) / a_safe);
    bool blocked0 = open_b || small_v || unreach || (tau0 < 0.0f);
    bool hit0 = (!blocked0) && (tau0 <= 1.0f);

    float Xf, Df, lg_pre;
    int   Cf;
    if (hit0) {
        int k1   = right ? c + 1 : c;
        int idx0 = right ? k1 : NCELL - k1;
        const float* Tt = right ? T0 : T1;
        const float* Gg = right ? G0 : G1;
        float r    = 1.0f - tau0;
        float base = Tt[idx0];
        int m = idx0;
        #pragma unroll
        for (int bit = 16; bit; bit >>= 1) {
            int cand = m + bit;
            bool ok = (cand <= NCELL) && ((Tt[cand] - base) <= r);
            m = ok ? cand : m;
        }
        float r2 = r - (Tt[m] - base);
        lg_pre = a * tau0 + (Gg[m] - Gg[idx0]);
        int knot = right ? m : NCELL - m;
        Cf = right ? knot : knot - 1;
        Xf = (float)knot * invN;
        Df = r2;
    } else {
        lg_pre = 0.0f; Cf = c; Xf = xs; Df = 1.0f;
    }

    float A  = ta[Cf], Bc = tb[Cf];
    float V  = A * Xf + Bc;
    bool  sA = fabsf(A) < eps;
    float A_safe = sA ? eps : A;
    float f  = sA ? Df : (expm1f(A * Df) / A_safe);
    z  = Xf + V * f;
    lg = lg_pre + A * Df;
}

// Per-block table setup (A = B@theta, per-cell crossing times, prefix sums).
__device__ __forceinline__ void block_setup(
        const float* __restrict__ theta, const float* __restrict__ B,
        float* ta, float* tb, float* taur_s, float* taul_s,
        float* T0, float* T1, float* G0, float* G1)
{
    const int tid = threadIdx.x;
    const float invN = 1.0f / (float)NCELL;

    if (tid < 2 * NCELL) {
        float acc = 0.f;
        #pragma unroll
        for (int j = 0; j < NCELL + 1; ++j)
            acc += B[tid * (NCELL + 1) + j] * theta[j];
        if (tid & 1) tb[tid >> 1] = acc;
        else         ta[tid >> 1] = acc;
    }
    __syncthreads();

    if (tid < NCELL) {
        int cc = tid;
        float a = ta[cc], b = tb[cc];
        float xl = (float)cc * invN, xr = (float)(cc + 1) * invN;
        taur_s[cc] = cross_tau(a, b, xl, xr, true,  cc == NCELL - 1);
        taul_s[cc] = cross_tau(a, b, xr, xl, false, cc == 0);
    }
    __syncthreads();

    if (tid < NCELL) {
        int lane = tid;
        float v0 = taur_s[lane];
        float v1 = taul_s[NCELL - 1 - lane];
        float g0 = ta[lane] * v0;
        float g1 = ta[NCELL - 1 - lane] * v1;
        #pragma unroll
        for (int off = 1; off < NCELL; off <<= 1) {
            float o0 = __shfl_up(v0, off, 64);
            float o1 = __shfl_up(v1, off, 64);
            float o2 = __shfl_up(g0, off, 64);
            float o3 = __shfl_up(g1, off, 64);
            if (lane >= off) { v0 += o0; v1 += o1; g0 += o2; g1 += o3; }
        }
        T0[lane + 1] = v0; T1[lane + 1] = v1;
        G0[lane + 1] = g0; G1[lane + 1] = g1;
        if (lane == 0) { T0[0] = 0.f; T1[0] = 0.f; G0[0] = 0.f; G1[0] = 0.f; }
    }
    __syncthreads();
}

// ---------- fused kernel: every block builds its table, then lerps ----------
// Round-13 structure (24.3 us), ONE change: NON-TEMPORAL STORES for z/lg
// (f32x4 ext-vector type -- HIP_vector_type rejected by the builtin).
// Outputs are write-once never-read: NT avoids L2 write-allocate churn
// (67 MB cycling the 32 MB aggregate L2 twice per dispatch). Loads stay
// normal: x is L3-resident across replays (FETCH 16.4 MB < 33.5 MB x).

__global__ __launch_bounds__(512) void cpab_kernel(
    const float* __restrict__ x,
    const float* __restrict__ theta,
    const float* __restrict__ B,
    float* __restrict__ z_out,
    float* __restrict__ lg_out,
    int n)
{
    __shared__ __half2 htab[KTAB + 1];
    __shared__ float ta[NCELL], tb[NCELL];
    __shared__ float taur_s[NCELL], taul_s[NCELL];
    __shared__ float T0[NCELL + 1], T1[NCELL + 1];
    __shared__ float G0[NCELL + 1], G1[NCELL + 1];

    const int tid = threadIdx.x;

    block_setup(theta, B, ta, tb, taur_s, taul_s, T0, T1, G0, G1);

    const float invK = 1.0f / (float)KTAB;
    if (tid <= KTAB) {
        float z, lg;
        solve_point((float)tid * invK, ta, tb, T0, T1, G0, G1, z, lg);
        htab[tid] = __floats2half2_rn(z, lg);
    }
    __syncthreads();

    const float Kf = (float)KTAB;
    const int gid    = blockIdx.x * blockDim.x + tid;
    const int stride = gridDim.x * blockDim.x;
    const int n4     = n >> 2;

    const f32x4* __restrict__ x4 = (const f32x4*)x;
    f32x4* __restrict__ z4 = (f32x4*)z_out;
    f32x4* __restrict__ l4 = (f32x4*)lg_out;

    #define LERP4(xv, zv, lv)                                   \
        {                                                       \
            _Pragma("unroll")                                   \
            for (int q = 0; q < 4; ++q) {                       \
                float t  = (xv)[q] * Kf;                        \
                float jf = floorf(t);                           \
                int   j  = min(max((int)jf, 0), KTAB - 1);      \
                float f  = t - (float)j;                        \
                float2 p0 = __half22float2(htab[j]);            \
                float2 p1 = __half22float2(htab[j + 1]);        \
                (zv)[q] = fmaf(f, p1.x - p0.x, p0.x);           \
                (lv)[q] = fmaf(f, p1.y - p0.y, p0.y);           \
            }                                                   \
        }

    // main unrolled body: 4 loads in flight, then 4 lerp+store groups
    const int i0 = gid;
    const int i1 = gid + stride;
    const int i2 = gid + 2 * stride;
    const int i3 = gid + 3 * stride;
    const bool v0 = i0 < n4, v1 = i1 < n4, v2 = i2 < n4, v3 = i3 < n4;
    f32x4 xv0, xv1, xv2, xv3;
    if (v0) xv0 = x4[i0];
    if (v1) xv1 = x4[i1];
    if (v2) xv2 = x4[i2];
    if (v3) xv3 = x4[i3];

    if (v0) { f32x4 zv, lv; LERP4(xv0, zv, lv);
              __builtin_nontemporal_store(zv, &z4[i0]);
              __builtin_nontemporal_store(lv, &l4[i0]); }
    if (v1) { f32x4 zv, lv; LERP4(xv1, zv, lv);
              __builtin_nontemporal_store(zv, &z4[i1]);
              __builtin_nontemporal_store(lv, &l4[i1]); }
    if (v2) { f32x4 zv, lv; LERP4(xv2, zv, lv);
              __builtin_nontemporal_store(zv, &z4[i2]);
              __builtin_nontemporal_store(lv, &l4[i2]); }
    if (v3) { f32x4 zv, lv; LERP4(xv3, zv, lv);
              __builtin_nontemporal_store(zv, &z4[i3]);
              __builtin_nontemporal_store(lv, &l4[i3]); }

    // residual (grid smaller than n4/4) + scalar tail (n % 4)
    for (int i = gid + 4 * stride; i < n4; i += stride) {
        f32x4 xv = x4[i], zv, lv;
        LERP4(xv, zv, lv);
        __builtin_nontemporal_store(zv, &z4[i]);
        __builtin_nontemporal_store(lv, &l4[i]);
    }
    for (int i = (n4 << 2) + gid; i < n; i += stride) {
        float t  = x[i] * Kf;
        float jf = floorf(t);
        int   j  = min(max((int)jf, 0), KTAB - 1);
        float f  = t - (float)j;
        float2 p0 = __half22float2(htab[j]);
        float2 p1 = __half22float2(htab[j + 1]);
        z_out[i]  = fmaf(f, p1.x - p0.x, p0.x);
        lg_out[i] = fmaf(f, p1.y - p0.y, p0.y);
    }
    #undef LERP4
}

extern "C" void kernel_launch(void* const* d_in, const int* in_sizes, int n_in,
                              void* d_out, int out_size, void* d_ws, size_t ws_size,
                              hipStream_t stream)
{
    const float* x     = (const float*)d_in[0];
    const float* theta = (const float*)d_in[1];
    const float* B     = (const float*)d_in[2];
    float* out = (float*)d_out;

    const int n = in_sizes[0];
    float* z_out  = out;
    float* lg_out = out + n;

    // 1024 blocks x 512 threads: 4 blocks/CU x 8 waves = 32 waves/CU,
    // LDS ~2 KB/block. n4 = 2.1M float4 -> exactly 4 iters/thread.
    cpab_kernel<<<1024, 512, 0, stream>>>(x, theta, B, z_out, lg_out, n);
}

// Round 15
// 20.737 us; speedup vs baseline: 1.5252x; 1.0721x over previous
//
#include <hip/hip_runtime.h>
#include <hip/hip_bf16.h>
#include <hip/hip_fp16.h>

#define NCELL 32
#define KTAB  256

typedef float f32x4 __attribute__((ext_vector_type(4)));

// ---------- proven round-2 closed form (unchanged numerics) ----------

__device__ __forceinline__ float cross_tau(float a, float b, float xs, float xb,
                                           bool need_right, bool open_b)
{
    const float eps    = 1e-10f;
    const float CLIPLO = -1.0f + 1e-6f;
    float v = a * xs + b;
    bool right = v > 0.0f;
    if (right != need_right) return 2.0f;
    bool small_a = fabsf(a) < eps;
    bool small_v = fabsf(v) < eps;
    float v_safe = small_v ? eps : v;
    float a_safe = small_a ? eps : a;
    float dxb = xb - xs;
    float arg_raw = a * dxb / v_safe;
    bool unreach = arg_raw <= CLIPLO;
    float tau = small_a ? (dxb / v_safe)
                        : (log1pf(fmaxf(arg_raw, CLIPLO)) / a_safe);
    if (open_b || small_v || unreach || (tau < 0.0f)) return 2.0f;
    return fminf(tau, 2.0f);
}

__device__ __forceinline__ void solve_point(float xs,
        const float* __restrict__ ta, const float* __restrict__ tb,
        const float* __restrict__ T0, const float* __restrict__ T1,
        const float* __restrict__ G0, const float* __restrict__ G1,
        float& z, float& lg)
{
    const float eps    = 1e-10f;
    const float CLIPLO = -1.0f + 1e-6f;
    const float invN   = 1.0f / (float)NCELL;

    int c = (int)floorf(xs * (float)NCELL);
    c = min(max(c, 0), NCELL - 1);
    float a = ta[c], b = tb[c];
    float v = a * xs + b;
    bool right = v > 0.0f;
    float xb = (right ? (float)(c + 1) : (float)c) * invN;
    bool open_b  = right ? (c == NCELL - 1) : (c == 0);
    bool small_a = fabsf(a) < eps;
    bool small_v = fabsf(v) < eps;
    float v_safe = small_v ? eps : v;
    float a_safe = small_a ? eps : a;
    float dxb = xb - xs;
    float arg_raw = a * dxb / v_safe;
    bool unreach = arg_raw <= CLIPLO;
    float tau0 = small_a ? (dxb / v_safe)
                         : (log1pf(fmaxf(arg_raw, CLIPLO)) / a_safe);
    bool blocked0 = open_b || small_v || unreach || (tau0 < 0.0f);
    bool hit0 = (!blocked0) && (tau0 <= 1.0f);

    float Xf, Df, lg_pre;
    int   Cf;
    if (hit0) {
        int k1   = right ? c + 1 : c;
        int idx0 = right ? k1 : NCELL - k1;
        const float* Tt = right ? T0 : T1;
        const float* Gg = right ? G0 : G1;
        float r    = 1.0f - tau0;
        float base = Tt[idx0];
        int m = idx0;
        #pragma unroll
        for (int bit = 16; bit; bit >>= 1) {
            int cand = m + bit;
            bool ok = (cand <= NCELL) && ((Tt[cand] - base) <= r);
            m = ok ? cand : m;
        }
        float r2 = r - (Tt[m] - base);
        lg_pre = a * tau0 + (Gg[m] - Gg[idx0]);
        int knot = right ? m : NCELL - m;
        Cf = right ? knot : knot - 1;
        Xf = (float)knot * invN;
        Df = r2;
    } else {
        lg_pre = 0.0f; Cf = c; Xf = xs; Df = 1.0f;
    }

    float A  = ta[Cf], Bc = tb[Cf];
    float V  = A * Xf + Bc;
    bool  sA = fabsf(A) < eps;
    float A_safe = sA ? eps : A;
    float f  = sA ? Df : (expm1f(A * Df) / A_safe);
    z  = Xf + V * f;
    lg = lg_pre + A * Df;
}

// Per-block table setup (A = B@theta, per-cell crossing times, prefix sums).
__device__ __forceinline__ void block_setup(
        const float* __restrict__ theta, const float* __restrict__ B,
        float* ta, float* tb, float* taur_s, float* taul_s,
        float* T0, float* T1, float* G0, float* G1)
{
    const int tid = threadIdx.x;
    const float invN = 1.0f / (float)NCELL;

    if (tid < 2 * NCELL) {
        float acc = 0.f;
        #pragma unroll
        for (int j = 0; j < NCELL + 1; ++j)
            acc += B[tid * (NCELL + 1) + j] * theta[j];
        if (tid & 1) tb[tid >> 1] = acc;
        else         ta[tid >> 1] = acc;
    }
    __syncthreads();

    if (tid < NCELL) {
        int cc = tid;
        float a = ta[cc], b = tb[cc];
        float xl = (float)cc * invN, xr = (float)(cc + 1) * invN;
        taur_s[cc] = cross_tau(a, b, xl, xr, true,  cc == NCELL - 1);
        taul_s[cc] = cross_tau(a, b, xr, xl, false, cc == 0);
    }
    __syncthreads();

    if (tid < NCELL) {
        int lane = tid;
        float v0 = taur_s[lane];
        float v1 = taul_s[NCELL - 1 - lane];
        float g0 = ta[lane] * v0;
        float g1 = ta[NCELL - 1 - lane] * v1;
        #pragma unroll
        for (int off = 1; off < NCELL; off <<= 1) {
            float o0 = __shfl_up(v0, off, 64);
            float o1 = __shfl_up(v1, off, 64);
            float o2 = __shfl_up(g0, off, 64);
            float o3 = __shfl_up(g1, off, 64);
            if (lane >= off) { v0 += o0; v1 += o1; g0 += o2; g1 += o3; }
        }
        T0[lane + 1] = v0; T1[lane + 1] = v1;
        G0[lane + 1] = g0; G1[lane + 1] = g1;
        if (lane == 0) { T0[0] = 0.f; T1[0] = 0.f; G0[0] = 0.f; G1[0] = 0.f; }
    }
    __syncthreads();
}

// ---------- fused kernel: build table, then PHASE-SPLIT stream ----------
// Round-14 structure (22.2 us), ONE change: the 4 x-loads per thread are
// issued right AFTER block_setup's last barrier and BEFORE the table-build
// solves -- load latency hides under the build VALU, and the loads drain at
// the table barrier (vmcnt(0) before s_barrier). The main loop is then a
// pure lerp + NT-store phase: read-burst then write-burst per CU instead of
// fine-grained R/W interleaving (HBM bus direction-turnaround suspect).
// (Round 9's failed version put loads BEFORE block_setup: its first barrier
// drained them with nothing to overlap, ahead of a then-4us build.)

__global__ __launch_bounds__(512) void cpab_kernel(
    const float* __restrict__ x,
    const float* __restrict__ theta,
    const float* __restrict__ B,
    float* __restrict__ z_out,
    float* __restrict__ lg_out,
    int n)
{
    __shared__ __half2 htab[KTAB + 1];
    __shared__ float ta[NCELL], tb[NCELL];
    __shared__ float taur_s[NCELL], taul_s[NCELL];
    __shared__ float T0[NCELL + 1], T1[NCELL + 1];
    __shared__ float G0[NCELL + 1], G1[NCELL + 1];

    const int tid = threadIdx.x;

    block_setup(theta, B, ta, tb, taur_s, taul_s, T0, T1, G0, G1);

    // ---- issue x-loads now: they fly during the table build ----
    const int gid    = blockIdx.x * blockDim.x + tid;
    const int stride = gridDim.x * blockDim.x;
    const int n4     = n >> 2;

    const f32x4* __restrict__ x4 = (const f32x4*)x;
    f32x4* __restrict__ z4 = (f32x4*)z_out;
    f32x4* __restrict__ l4 = (f32x4*)lg_out;

    const int i0 = gid;
    const int i1 = gid + stride;
    const int i2 = gid + 2 * stride;
    const int i3 = gid + 3 * stride;
    const bool v0 = i0 < n4, v1 = i1 < n4, v2 = i2 < n4, v3 = i3 < n4;
    f32x4 xv0, xv1, xv2, xv3;
    if (v0) xv0 = x4[i0];
    if (v1) xv1 = x4[i1];
    if (v2) xv2 = x4[i2];
    if (v3) xv3 = x4[i3];

    // ---- table build (VALU) overlaps the in-flight loads ----
    const float invK = 1.0f / (float)KTAB;
    if (tid <= KTAB) {
        float z, lg;
        solve_point((float)tid * invK, ta, tb, T0, T1, G0, G1, z, lg);
        htab[tid] = __floats2half2_rn(z, lg);
    }
    __syncthreads();   // drains lgkm + vmcnt: table ready AND x in registers

    const float Kf = (float)KTAB;

    #define LERP4(xv, zv, lv)                                   \
        {                                                       \
            _Pragma("unroll")                                   \
            for (int q = 0; q < 4; ++q) {                       \
                float t  = (xv)[q] * Kf;                        \
                float jf = floorf(t);                           \
                int   j  = min(max((int)jf, 0), KTAB - 1);      \
                float f  = t - (float)j;                        \
                float2 p0 = __half22float2(htab[j]);            \
                float2 p1 = __half22float2(htab[j + 1]);        \
                (zv)[q] = fmaf(f, p1.x - p0.x, p0.x);           \
                (lv)[q] = fmaf(f, p1.y - p0.y, p0.y);           \
            }                                                   \
        }

    // ---- pure lerp + NT-store phase ----
    if (v0) { f32x4 zv, lv; LERP4(xv0, zv, lv);
              __builtin_nontemporal_store(zv, &z4[i0]);
              __builtin_nontemporal_store(lv, &l4[i0]); }
    if (v1) { f32x4 zv, lv; LERP4(xv1, zv, lv);
              __builtin_nontemporal_store(zv, &z4[i1]);
              __builtin_nontemporal_store(lv, &l4[i1]); }
    if (v2) { f32x4 zv, lv; LERP4(xv2, zv, lv);
              __builtin_nontemporal_store(zv, &z4[i2]);
              __builtin_nontemporal_store(lv, &l4[i2]); }
    if (v3) { f32x4 zv, lv; LERP4(xv3, zv, lv);
              __builtin_nontemporal_store(zv, &z4[i3]);
              __builtin_nontemporal_store(lv, &l4[i3]); }

    // residual (grid smaller than n4/4) + scalar tail (n % 4)
    for (int i = gid + 4 * stride; i < n4; i += stride) {
        f32x4 xv = x4[i], zv, lv;
        LERP4(xv, zv, lv);
        __builtin_nontemporal_store(zv, &z4[i]);
        __builtin_nontemporal_store(lv, &l4[i]);
    }
    for (int i = (n4 << 2) + gid; i < n; i += stride) {
        float t  = x[i] * Kf;
        float jf = floorf(t);
        int   j  = min(max((int)jf, 0), KTAB - 1);
        float f  = t - (float)j;
        float2 p0 = __half22float2(htab[j]);
        float2 p1 = __half22float2(htab[j + 1]);
        z_out[i]  = fmaf(f, p1.x - p0.x, p0.x);
        lg_out[i] = fmaf(f, p1.y - p0.y, p0.y);
    }
    #undef LERP4
}

extern "C" void kernel_launch(void* const* d_in, const int* in_sizes, int n_in,
                              void* d_out, int out_size, void* d_ws, size_t ws_size,
                              hipStream_t stream)
{
    const float* x     = (const float*)d_in[0];
    const float* theta = (const float*)d_in[1];
    const float* B     = (const float*)d_in[2];
    float* out = (float*)d_out;

    const int n = in_sizes[0];
    float* z_out  = out;
    float* lg_out = out + n;

    // 1024 blocks x 512 threads: 4 blocks/CU x 8 waves = 32 waves/CU,
    // LDS ~2 KB/block. n4 = 2.1M float4 -> exactly 4 iters/thread.
    cpab_kernel<<<1024, 512, 0, stream>>>(x, theta, B, z_out, lg_out, n);
}